// Round 8
// baseline (126.252 us; speedup 1.0000x reference)
//
#include <hip/hip_runtime.h>
#include <stdint.h>

// BinaryTreeLogicNet: out = sigmoid(tree_gcd(sigmoid(x @ W^T - 2)) * w_out + b_out)
// M=65536 rows, L=256 leaves.
// R8: split into streaming-optimal prep + VALU-free MFMA main.
//   prep (4160 blocks x 256 thr, grid-stride, coalesced, tiny VGPR):
//     - blocks 0..4095: x fp32 -> bf16 image (32 MB) in d_ws (same f2bf RNE)
//     - blocks 4096..4159: W -> R7's proven swizzled 128 KB bf16 image + params
//   btln_main: R7 structure (512 thr, 8 waves x 16 rows, 2 blocks/CU,
//     global_load_lds double-buffered W tiles) but A-frags are ONE b128 load
//     each from the bf16 x-image -> zero pack/cvt VALU in the whole main loop.
//     x-image and W-image are L2/L3-warm from prep -> main HBM traffic ~0.
//   Tests the "main-loop VALU/byte bloat" theory; prep and main separately
//   visible in rocprof.

#define EPS 1e-6f
#define LOG2E 1.44269504088896340736f
#define XIMG_BYTES (65536ull * 256ull * 2ull)   // 32 MB bf16 x image
#define WOFF XIMG_BYTES                          // W image offset in d_ws
#define PARAM_OFF 131072                         // params offset within W image

typedef __attribute__((ext_vector_type(8))) short short8;
typedef __attribute__((ext_vector_type(4))) short short4_t;
typedef __attribute__((ext_vector_type(4))) float float4_t;

__device__ __forceinline__ float fast_sigmoid(float z) {
    float e = __builtin_amdgcn_exp2f(-z * LOG2E);
    return __builtin_amdgcn_rcpf(1.0f + e);
}

__device__ __forceinline__ short f2bf(float f) {   // fp32 -> bf16 RNE
    uint32_t u = __builtin_bit_cast(uint32_t, f);
    u += 0x7FFFu + ((u >> 16) & 1u);
    return (short)(u >> 16);
}

__device__ __forceinline__ float ggcd(float l, float r, float lam) {
    float a = fabsf(l) + EPS;
    float b = fabsf(r) + EPS;
    float mn = fminf(a, b);
    float mx = fmaxf(a, b);
    return fmaf(lam, mn - mx, mx);   // lam*mn + (1-lam)*mx
}

__device__ __forceinline__ void lds16(const void* g, void* l) {
    __builtin_amdgcn_global_load_lds(
        (const __attribute__((address_space(1))) unsigned int*)g,
        (__attribute__((address_space(3))) unsigned int*)l, 16, 0, 0);
}

// tree levels 1-4 on one 16-acc row-group; acc consumed in place
__device__ __forceinline__ void tree_reduce(float4_t acc[16], int c0,
                                            const float4* pv, float res[4]) {
    #pragma unroll
    for (int t = 0; t < 16; ++t) {
        #pragma unroll
        for (int r = 0; r < 4; ++r) acc[t][r] = fast_sigmoid(acc[t][r] - 2.0f);
    }
    #pragma unroll
    for (int tp = 0; tp < 8; ++tp) {          // level 1 (off 0)
        float4 p = pv[c0 * 8 + tp];
        #pragma unroll
        for (int r = 0; r < 4; ++r)
            acc[tp][r] = ggcd(acc[2*tp][r] * p.x, acc[2*tp+1][r] * p.y, p.z);
    }
    #pragma unroll
    for (int tp = 0; tp < 4; ++tp) {          // level 2 (off 128)
        float4 p = pv[128 + c0 * 4 + tp];
        #pragma unroll
        for (int r = 0; r < 4; ++r)
            acc[tp][r] = ggcd(acc[2*tp][r] * p.x, acc[2*tp+1][r] * p.y, p.z);
    }
    #pragma unroll
    for (int tp = 0; tp < 2; ++tp) {          // level 3 (off 192)
        float4 p = pv[192 + c0 * 2 + tp];
        #pragma unroll
        for (int r = 0; r < 4; ++r)
            acc[tp][r] = ggcd(acc[2*tp][r] * p.x, acc[2*tp+1][r] * p.y, p.z);
    }
    {                                          // level 4 (off 224)
        float4 p = pv[224 + c0];
        #pragma unroll
        for (int r = 0; r < 4; ++r)
            res[r] = ggcd(acc[0][r] * p.x, acc[1][r] * p.y, p.z);
    }
}

// ---- prep: x -> bf16 image; W -> swizzled bf16 image (R7 layout) + params ----
__global__ __launch_bounds__(256)
void prep(const float* __restrict__ x, const float* __restrict__ Wl,
          const float* __restrict__ wts, const float* __restrict__ bia,
          char* __restrict__ ws) {
    const int bid = blockIdx.x;
    if (bid < 4096) {
        // x convert: 1024 float4 per block, fully coalesced
        const float4* xin = (const float4*)x;
        short4_t* xout = (short4_t*)ws;
        const int base = bid * 1024 + threadIdx.x;
        #pragma unroll
        for (int j = 0; j < 4; ++j) {
            int i = base + j * 256;
            float4 v = xin[i];
            short4_t s4;
            s4.x = f2bf(v.x); s4.y = f2bf(v.y); s4.z = f2bf(v.z); s4.w = f2bf(v.w);
            xout[i] = s4;
        }
    } else {
        // W image byte a (a = kt*32768 + j*128 + cpos*16 + h*8):
        //   W[swap(j)][kt*64 + (cpos^(j&7))*8 + h*4 ..+4) as bf16x4
        char* img = ws + WOFF;
        int i = (bid - 4096) * 256 + threadIdx.x;   // 0..16383, 8 B each
        int a = i * 8;
        int kt   = a >> 15;
        int s    = a & 32767;
        int j    = s >> 7;
        int b    = s & 127;
        int cpos = b >> 4;
        int h    = (b >> 3) & 1;
        int c    = cpos ^ (j & 7);
        int k    = kt * 64 + c * 8 + h * 4;
        int src  = ((j & 15) << 4) | (j >> 4);      // nibble-swap (involution)
        float4 w4 = *(const float4*)&Wl[src * 256 + k];
        short4_t s4;
        s4.x = f2bf(w4.x); s4.y = f2bf(w4.y); s4.z = f2bf(w4.z); s4.w = f2bf(w4.w);
        *(short4_t*)&img[a] = s4;

        if (i < 255) {
            float4* pv = (float4*)(img + PARAM_OFF);
            pv[i] = make_float4(wts[2 * i], wts[2 * i + 1], fast_sigmoid(bia[i]), 0.f);
        } else if (i == 255) {
            ((float4*)(img + PARAM_OFF))[255] = make_float4(0.f, 0.f, 0.f, 0.f);
        }
    }
}

// ---- main kernel: zero cvt/pack VALU in the loop ----
__global__ __launch_bounds__(512, 4)
void btln_main(const char* __restrict__ ws,
               const float* __restrict__ wout, const float* __restrict__ bout,
               float* __restrict__ out) {
    __shared__ short Wt[2][16384];           // 2 x 32 KB W K-tiles
    __shared__ float4 pv[256];               // 4 KB packed (w0,w1,lam)

    const short* x_bf = (const short*)ws;
    const char*  img  = ws + WOFF;

    const int tid  = threadIdx.x;
    const int lane = tid & 63;
    const int wv   = tid >> 6;               // wave 0..7
    const int c0   = lane & 15;
    const int q    = lane >> 4;

    if (tid < 256) pv[tid] = ((const float4*)(img + PARAM_OFF))[tid];

    // issue tile 0 (wave wv owns 4 KB: 4 x (64 lanes x 16 B))
    {
        const char* g = img + wv * 4096 + lane * 16;
        char* l = (char*)&Wt[0][wv * 2048];
        #pragma unroll
        for (int it = 0; it < 4; ++it)
            lds16(g + it * 1024, l + it * 1024);
    }

    const int rowbase = blockIdx.x * 128 + wv * 16;
    const short8* xr8 = (const short8*)(x_bf + (size_t)(rowbase + c0) * 256);

    float4_t acc[16];
    #pragma unroll
    for (int t = 0; t < 16; ++t) acc[t] = (float4_t){0.f, 0.f, 0.f, 0.f};

    // A-frags for tile 0: ONE b128 each (frag layout: row c0, k q*8.. / 32+q*8..)
    short8 a0 = xr8[q];
    short8 a1 = xr8[q + 4];

    __syncthreads();                          // tile 0 resident

    const int vx = c0 & 7;
    #pragma unroll 1
    for (int kt = 0; kt < 4; ++kt) {
        const short* cur = Wt[kt & 1];
        if (kt < 3) {                         // issue tile kt+1 into other buffer
            const char* g = img + (kt + 1) * 32768 + wv * 4096 + lane * 16;
            char* l = (char*)&Wt[(kt + 1) & 1][wv * 2048];
            #pragma unroll
            for (int it = 0; it < 4; ++it)
                lds16(g + it * 1024, l + it * 1024);
        }
        // prefetch next tile's A-frags (kt=3: redundant, harmless)
        const int kb = (kt < 3 ? kt + 1 : 3) * 8;
        short8 n0 = xr8[kb + q];
        short8 n1 = xr8[kb + 4 + q];

        #pragma unroll
        for (int t = 0; t < 16; ++t) {
            const short* base = &cur[(t * 16 + c0) * 64];
            short8 bf0 = *(const short8*)&base[(q ^ vx) * 8];        // chunk q
            short8 bf1 = *(const short8*)&base[((q + 4) ^ vx) * 8];  // chunk q+4
            acc[t] = __builtin_amdgcn_mfma_f32_16x16x32_bf16(a0, bf0, acc[t], 0, 0, 0);
            acc[t] = __builtin_amdgcn_mfma_f32_16x16x32_bf16(a1, bf1, acc[t], 0, 0, 0);
        }
        __syncthreads();                      // tile kt consumed; kt+1 landed
        a0 = n0; a1 = n1;
    }

    // ---- epilogue: leaf sigmoid + tree (acc[t][r]: row q*4+r, leaf c0*16+t) ----
    float res[4];
    tree_reduce(acc, c0, pv, res);

    const int offs[4] = {240, 248, 252, 254};
    #pragma unroll
    for (int k = 0; k < 4; ++k) {             // levels 5-8: butterfly across c0
        float4 p = pv[offs[k] + (c0 >> (k + 1))];
        bool isLeft = ((c0 >> k) & 1) == 0;
        #pragma unroll
        for (int r = 0; r < 4; ++r) {
            float other = __shfl_xor(res[r], 1 << k, 64);
            float lf = isLeft ? res[r] : other;
            float rt = isLeft ? other  : res[r];
            res[r] = ggcd(lf * p.x, rt * p.y, p.z);
        }
    }

    if (c0 == 0) {
        const float wo = wout[0];
        const float bo = bout[0];
        #pragma unroll
        for (int r = 0; r < 4; ++r)
            out[rowbase + q * 4 + r] = fast_sigmoid(fmaf(res[r], wo, bo));
    }
}

extern "C" void kernel_launch(void* const* d_in, const int* in_sizes, int n_in,
                              void* d_out, int out_size, void* d_ws, size_t ws_size,
                              hipStream_t stream) {
    const float* x   = (const float*)d_in[0];
    const float* Wl  = (const float*)d_in[1];
    const float* wts = (const float*)d_in[2];
    const float* bia = (const float*)d_in[3];
    const float* wo  = (const float*)d_in[4];
    const float* bo  = (const float*)d_in[5];
    float* out = (float*)d_out;
    char* ws = (char*)d_ws;     // 32 MB x-image + 128 KB W-image + 4 KB params

    prep<<<dim3(4096 + 64), dim3(256), 0, stream>>>(x, Wl, wts, bia, ws);

    const int rows = out_size;                // 65536
    dim3 grid(rows / 128), block(512);        // 512 blocks x 8 waves, 2 blocks/CU
    btln_main<<<grid, block, 0, stream>>>(ws, wo, bo, out);
}

// Round 9
// 117.980 us; speedup vs baseline: 1.0701x; 1.0701x over previous
//
#include <hip/hip_runtime.h>
#include <stdint.h>

// BinaryTreeLogicNet: out = sigmoid(tree_gcd(sigmoid(x @ W^T - 2)) * w_out + b_out)
// M=65536 rows, L=256 leaves.
// R9: maximize INDEPENDENT blocks per CU (barrier desynchronization).
//   Evidence: R6 (1 blk/CU) kernel 42.8us @ 70% idle; R7 (2 blk/CU) ~31us;
//   all traffic/VALU theories falsified (R4/R6/R7/R8). Theory: per-kt
//   barrier+vmcnt drain parks the whole CU; independent blocks overlap it.
//   - 256 thr (4 waves x 16 rows = 64 rows/block), 1024 blocks.
//   - K-tile = 32 cols (16 KB), double-buffered global_load_lds; LDS 37 KB
//     -> 4 blocks/CU = 16 waves in 4 independent barrier domains.
//   - Pre-kernel: W -> 8 x 16KB bf16 K-tile images, nibble-swap rows,
//     chunk^(j&3) XOR swizzle baked in; + packed (w0,w1,lam) param table.
//   - A: fp32 gather one tile ahead + pack (proven R7 path; VGPR ~100).
//   Epilogue identical to R4-R8 (absmax 0.00390625).

#define EPS 1e-6f
#define LOG2E 1.44269504088896340736f
#define PARAM_OFF 131072            // byte offset of param table in img

typedef __attribute__((ext_vector_type(8))) short short8;
typedef __attribute__((ext_vector_type(4))) short short4_t;
typedef __attribute__((ext_vector_type(4))) float float4_t;

__device__ __forceinline__ float fast_sigmoid(float z) {
    float e = __builtin_amdgcn_exp2f(-z * LOG2E);
    return __builtin_amdgcn_rcpf(1.0f + e);
}

__device__ __forceinline__ short f2bf(float f) {   // fp32 -> bf16 RNE
    uint32_t u = __builtin_bit_cast(uint32_t, f);
    u += 0x7FFFu + ((u >> 16) & 1u);
    return (short)(u >> 16);
}

__device__ __forceinline__ short8 pack8(float4 a, float4 b) {
    short8 s;
    s[0] = f2bf(a.x); s[1] = f2bf(a.y); s[2] = f2bf(a.z); s[3] = f2bf(a.w);
    s[4] = f2bf(b.x); s[5] = f2bf(b.y); s[6] = f2bf(b.z); s[7] = f2bf(b.w);
    return s;
}

__device__ __forceinline__ float ggcd(float l, float r, float lam) {
    float a = fabsf(l) + EPS;
    float b = fabsf(r) + EPS;
    float mn = fminf(a, b);
    float mx = fmaxf(a, b);
    return fmaf(lam, mn - mx, mx);   // lam*mn + (1-lam)*mx
}

__device__ __forceinline__ void lds16(const void* g, void* l) {
    __builtin_amdgcn_global_load_lds(
        (const __attribute__((address_space(1))) unsigned int*)g,
        (__attribute__((address_space(3))) unsigned int*)l, 16, 0, 0);
}

// tree levels 1-4 on one 16-acc row-group; acc consumed in place
__device__ __forceinline__ void tree_reduce(float4_t acc[16], int c0,
                                            const float4* pv, float res[4]) {
    #pragma unroll
    for (int t = 0; t < 16; ++t) {
        #pragma unroll
        for (int r = 0; r < 4; ++r) acc[t][r] = fast_sigmoid(acc[t][r] - 2.0f);
    }
    #pragma unroll
    for (int tp = 0; tp < 8; ++tp) {          // level 1 (off 0)
        float4 p = pv[c0 * 8 + tp];
        #pragma unroll
        for (int r = 0; r < 4; ++r)
            acc[tp][r] = ggcd(acc[2*tp][r] * p.x, acc[2*tp+1][r] * p.y, p.z);
    }
    #pragma unroll
    for (int tp = 0; tp < 4; ++tp) {          // level 2 (off 128)
        float4 p = pv[128 + c0 * 4 + tp];
        #pragma unroll
        for (int r = 0; r < 4; ++r)
            acc[tp][r] = ggcd(acc[2*tp][r] * p.x, acc[2*tp+1][r] * p.y, p.z);
    }
    #pragma unroll
    for (int tp = 0; tp < 2; ++tp) {          // level 3 (off 192)
        float4 p = pv[192 + c0 * 2 + tp];
        #pragma unroll
        for (int r = 0; r < 4; ++r)
            acc[tp][r] = ggcd(acc[2*tp][r] * p.x, acc[2*tp+1][r] * p.y, p.z);
    }
    {                                          // level 4 (off 224)
        float4 p = pv[224 + c0];
        #pragma unroll
        for (int r = 0; r < 4; ++r)
            res[r] = ggcd(acc[0][r] * p.x, acc[1][r] * p.y, p.z);
    }
}

// ---- pre-kernel: W -> 8 x 16KB K-tile bf16 images + packed params ----
// img byte a (a = t*16384 + j*64 + cpos*16 + h*8):
//   holds W[swap(j)][t*32 + (cpos^(j&3))*8 + h*4 .. +4) as bf16x4
__global__ __launch_bounds__(256)
void convert_w(const float* __restrict__ Wl, const float* __restrict__ wts,
               const float* __restrict__ bia, char* __restrict__ img) {
    int i = blockIdx.x * 256 + threadIdx.x;   // 64 blocks -> 16384 threads x 8 B
    int a = i * 8;
    int t    = a >> 14;
    int s    = a & 16383;
    int j    = s >> 6;
    int b    = s & 63;
    int cpos = b >> 4;
    int h    = (b >> 3) & 1;
    int c    = cpos ^ (j & 3);
    int k    = t * 32 + c * 8 + h * 4;
    int src  = ((j & 15) << 4) | (j >> 4);    // nibble-swap (involution)
    float4 w4 = *(const float4*)&Wl[src * 256 + k];
    short4_t s4;
    s4.x = f2bf(w4.x); s4.y = f2bf(w4.y); s4.z = f2bf(w4.z); s4.w = f2bf(w4.w);
    *(short4_t*)&img[a] = s4;

    if (i < 255) {
        float4* pv = (float4*)(img + PARAM_OFF);
        pv[i] = make_float4(wts[2 * i], wts[2 * i + 1], fast_sigmoid(bia[i]), 0.f);
    } else if (i == 255) {
        ((float4*)(img + PARAM_OFF))[255] = make_float4(0.f, 0.f, 0.f, 0.f);
    }
}

// ---- main kernel: 256 thr, 4 waves x 16 rows, 4 blocks/CU ----
__global__ __launch_bounds__(256, 4)
void btln_main(const float* __restrict__ x, const char* __restrict__ img,
               const float* __restrict__ wout, const float* __restrict__ bout,
               float* __restrict__ out) {
    __shared__ short Wt[2][8192];            // 2 x 16 KB W K-tiles
    __shared__ float4 pv[256];               // 4 KB packed (w0,w1,lam)

    const int tid  = threadIdx.x;
    const int lane = tid & 63;
    const int wv   = tid >> 6;               // wave 0..3
    const int c0   = lane & 15;
    const int q    = lane >> 4;

    pv[tid] = ((const float4*)(img + PARAM_OFF))[tid];

    // issue tile 0: 16 KB via glds16, 4 passes of 256 thr x 16 B
    #pragma unroll
    for (int p = 0; p < 4; ++p)
        lds16(img + p * 4096 + tid * 16, (char*)Wt[0] + p * 4096 + tid * 16);

    const int rowbase = blockIdx.x * 64 + wv * 16;
    const float* xr = x + (size_t)(rowbase + c0) * 256;

    float4_t acc[16];
    #pragma unroll
    for (int t = 0; t < 16; ++t) acc[t] = (float4_t){0.f, 0.f, 0.f, 0.f};

    // A-frag for tile 0 (row c0, k q*8..q*8+7)
    float4 a0 = *(const float4*)(xr + q * 8);
    float4 a1 = *(const float4*)(xr + q * 8 + 4);

    __syncthreads();                          // tile 0 resident

    const int vx = c0 & 3;
    #pragma unroll 1
    for (int kt = 0; kt < 8; ++kt) {
        const short* cur = Wt[kt & 1];
        if (kt < 7) {                         // issue tile kt+1 into other buffer
            const char* g = img + (kt + 1) * 16384 + tid * 16;
            char* l = (char*)Wt[(kt + 1) & 1] + tid * 16;
            #pragma unroll
            for (int p = 0; p < 4; ++p)
                lds16(g + p * 4096, l + p * 4096);
        }
        // prefetch next tile's A-frag (kt=7: redundant reload, harmless)
        const int kn = (kt < 7 ? kt + 1 : 7) * 32;
        float4 n0 = *(const float4*)(xr + kn + q * 8);
        float4 n1 = *(const float4*)(xr + kn + q * 8 + 4);

        short8 af = pack8(a0, a1);
        #pragma unroll
        for (int t = 0; t < 16; ++t) {
            const short* base = &cur[(t * 16 + c0) * 32];   // 64 B per row
            short8 bf = *(const short8*)&base[(q ^ vx) * 8];
            acc[t] = __builtin_amdgcn_mfma_f32_16x16x32_bf16(af, bf, acc[t], 0, 0, 0);
        }
        __syncthreads();                      // tile kt consumed; kt+1 landed
        a0 = n0; a1 = n1;
    }

    // ---- epilogue: leaf sigmoid + tree (acc[t][r]: row q*4+r, leaf c0*16+t) ----
    float res[4];
    tree_reduce(acc, c0, pv, res);

    const int offs[4] = {240, 248, 252, 254};
    #pragma unroll
    for (int k = 0; k < 4; ++k) {             // levels 5-8: butterfly across c0
        float4 p = pv[offs[k] + (c0 >> (k + 1))];
        bool isLeft = ((c0 >> k) & 1) == 0;
        #pragma unroll
        for (int r = 0; r < 4; ++r) {
            float other = __shfl_xor(res[r], 1 << k, 64);
            float lf = isLeft ? res[r] : other;
            float rt = isLeft ? other  : res[r];
            res[r] = ggcd(lf * p.x, rt * p.y, p.z);
        }
    }

    if (c0 == 0) {
        const float wo = wout[0];
        const float bo = bout[0];
        #pragma unroll
        for (int r = 0; r < 4; ++r)
            out[rowbase + q * 4 + r] = fast_sigmoid(fmaf(res[r], wo, bo));
    }
}

extern "C" void kernel_launch(void* const* d_in, const int* in_sizes, int n_in,
                              void* d_out, int out_size, void* d_ws, size_t ws_size,
                              hipStream_t stream) {
    const float* x   = (const float*)d_in[0];
    const float* Wl  = (const float*)d_in[1];
    const float* wts = (const float*)d_in[2];
    const float* bia = (const float*)d_in[3];
    const float* wo  = (const float*)d_in[4];
    const float* bo  = (const float*)d_in[5];
    float* out = (float*)d_out;
    char* img = (char*)d_ws;                  // 128 KB W image + 4 KB params

    convert_w<<<dim3(64), dim3(256), 0, stream>>>(Wl, wts, bia, img);

    const int rows = out_size;                // 65536
    dim3 grid(rows / 64), block(256);         // 1024 blocks x 4 waves, 4 blocks/CU
    btln_main<<<grid, block, 0, stream>>>(x, img, wo, bo, out);
}

// Round 10
// 115.691 us; speedup vs baseline: 1.0913x; 1.0198x over previous
//
#include <hip/hip_runtime.h>
#include <stdint.h>

// BinaryTreeLogicNet: out = sigmoid(tree_gcd(sigmoid(x @ W^T - 2)) * w_out + b_out)
// M=65536 rows, L=256 leaves.
// R10: R7 (best, 113.7) + PHASE-STAGGERED co-resident blocks.
//   Lockstep theory: all waves/blocks on a CU hit vmcnt(0)+barrier in phase
//   (wave-overlap factor fit: ~1.6 of 8-16 resident). Odd blocks rotate the
//   K-loop start to kt=2 so the 2 blocks/CU prefetch/compute in anti-phase.
//   Also removes R7's redundant kt=3 A-reload. Everything else identical
//   (swizzled W image via global_load_lds double-buffer, A fp32 gather 1-tile
//   ahead, register tree epilogue; absmax 0.00390625 lineage).

#define EPS 1e-6f
#define LOG2E 1.44269504088896340736f
#define PARAM_OFF 131072            // byte offset of param table in img

typedef __attribute__((ext_vector_type(8))) short short8;
typedef __attribute__((ext_vector_type(4))) short short4_t;
typedef __attribute__((ext_vector_type(4))) float float4_t;

__device__ __forceinline__ float fast_sigmoid(float z) {
    float e = __builtin_amdgcn_exp2f(-z * LOG2E);
    return __builtin_amdgcn_rcpf(1.0f + e);
}

__device__ __forceinline__ short f2bf(float f) {   // fp32 -> bf16 RNE
    uint32_t u = __builtin_bit_cast(uint32_t, f);
    u += 0x7FFFu + ((u >> 16) & 1u);
    return (short)(u >> 16);
}

__device__ __forceinline__ short8 pack8(float4 a, float4 b) {
    short8 s;
    s[0] = f2bf(a.x); s[1] = f2bf(a.y); s[2] = f2bf(a.z); s[3] = f2bf(a.w);
    s[4] = f2bf(b.x); s[5] = f2bf(b.y); s[6] = f2bf(b.z); s[7] = f2bf(b.w);
    return s;
}

__device__ __forceinline__ float ggcd(float l, float r, float lam) {
    float a = fabsf(l) + EPS;
    float b = fabsf(r) + EPS;
    float mn = fminf(a, b);
    float mx = fmaxf(a, b);
    return fmaf(lam, mn - mx, mx);   // lam*mn + (1-lam)*mx
}

__device__ __forceinline__ void lds16(const void* g, void* l) {
    __builtin_amdgcn_global_load_lds(
        (const __attribute__((address_space(1))) unsigned int*)g,
        (__attribute__((address_space(3))) unsigned int*)l, 16, 0, 0);
}

// tree levels 1-4 on one 16-acc row-group; acc consumed in place
__device__ __forceinline__ void tree_reduce(float4_t acc[16], int c0,
                                            const float4* pv, float res[4]) {
    #pragma unroll
    for (int t = 0; t < 16; ++t) {
        #pragma unroll
        for (int r = 0; r < 4; ++r) acc[t][r] = fast_sigmoid(acc[t][r] - 2.0f);
    }
    #pragma unroll
    for (int tp = 0; tp < 8; ++tp) {          // level 1 (off 0)
        float4 p = pv[c0 * 8 + tp];
        #pragma unroll
        for (int r = 0; r < 4; ++r)
            acc[tp][r] = ggcd(acc[2*tp][r] * p.x, acc[2*tp+1][r] * p.y, p.z);
    }
    #pragma unroll
    for (int tp = 0; tp < 4; ++tp) {          // level 2 (off 128)
        float4 p = pv[128 + c0 * 4 + tp];
        #pragma unroll
        for (int r = 0; r < 4; ++r)
            acc[tp][r] = ggcd(acc[2*tp][r] * p.x, acc[2*tp+1][r] * p.y, p.z);
    }
    #pragma unroll
    for (int tp = 0; tp < 2; ++tp) {          // level 3 (off 192)
        float4 p = pv[192 + c0 * 2 + tp];
        #pragma unroll
        for (int r = 0; r < 4; ++r)
            acc[tp][r] = ggcd(acc[2*tp][r] * p.x, acc[2*tp+1][r] * p.y, p.z);
    }
    {                                          // level 4 (off 224)
        float4 p = pv[224 + c0];
        #pragma unroll
        for (int r = 0; r < 4; ++r)
            res[r] = ggcd(acc[0][r] * p.x, acc[1][r] * p.y, p.z);
    }
}

// ---- pre-kernel: swizzled bf16 W image + packed params (R7 layout) ----
// img byte a (a = kt*32768 + j*128 + cpos*16 + h*8):
//   holds W[swap(j)][kt*64 + (cpos^(j&7))*8 + h*4 .. +4) as bf16x4
__global__ __launch_bounds__(256)
void convert_w(const float* __restrict__ Wl, const float* __restrict__ wts,
               const float* __restrict__ bia, char* __restrict__ img) {
    int i = blockIdx.x * 256 + threadIdx.x;   // 64 blocks -> 16384 threads x 8 B
    int a = i * 8;
    int kt   = a >> 15;
    int s    = a & 32767;
    int j    = s >> 7;
    int b    = s & 127;
    int cpos = b >> 4;
    int h    = (b >> 3) & 1;
    int c    = cpos ^ (j & 7);
    int k    = kt * 64 + c * 8 + h * 4;
    int src  = ((j & 15) << 4) | (j >> 4);    // nibble-swap (involution)
    float4 w4 = *(const float4*)&Wl[src * 256 + k];
    short4_t s4;
    s4.x = f2bf(w4.x); s4.y = f2bf(w4.y); s4.z = f2bf(w4.z); s4.w = f2bf(w4.w);
    *(short4_t*)&img[a] = s4;

    if (i < 255) {
        float4* pv = (float4*)(img + PARAM_OFF);
        pv[i] = make_float4(wts[2 * i], wts[2 * i + 1], fast_sigmoid(bia[i]), 0.f);
    } else if (i == 255) {
        ((float4*)(img + PARAM_OFF))[255] = make_float4(0.f, 0.f, 0.f, 0.f);
    }
}

// ---- main kernel ----
__global__ __launch_bounds__(512, 4)
void btln_main(const float* __restrict__ x, const char* __restrict__ img,
               const float* __restrict__ wout, const float* __restrict__ bout,
               float* __restrict__ out) {
    __shared__ short Wt[2][16384];           // 2 x 32 KB W K-tiles
    __shared__ float4 pv[256];               // 4 KB packed (w0,w1,lam)

    const int tid  = threadIdx.x;
    const int lane = tid & 63;
    const int wv   = tid >> 6;               // wave 0..7
    const int c0   = lane & 15;
    const int q    = lane >> 4;

    // anti-phase: odd blocks start their K-loop half a revolution later
    const int phase = (blockIdx.x & 1) * 2;

    if (tid < 256) pv[tid] = ((const float4*)(img + PARAM_OFF))[tid];

    // issue first tile (tix = phase)
    {
        const char* g = img + phase * 32768 + wv * 4096 + lane * 16;
        char* l = (char*)&Wt[0][wv * 2048];
        #pragma unroll
        for (int it = 0; it < 4; ++it)
            lds16(g + it * 1024, l + it * 1024);
    }

    const int rowbase = blockIdx.x * 128 + wv * 16;
    const float* xr = x + (size_t)(rowbase + c0) * 256;

    float4_t acc[16];
    #pragma unroll
    for (int t = 0; t < 16; ++t) acc[t] = (float4_t){0.f, 0.f, 0.f, 0.f};

    // A-frags for first tile (frag layout: row c0, k-local q*8.. / 32+q*8..)
    float4 a0 = *(const float4*)(xr + phase * 64 + q * 8);
    float4 a1 = *(const float4*)(xr + phase * 64 + q * 8 + 4);
    float4 a2 = *(const float4*)(xr + phase * 64 + 32 + q * 8);
    float4 a3 = *(const float4*)(xr + phase * 64 + 32 + q * 8 + 4);

    __syncthreads();                          // first tile resident

    const int vx = c0 & 7;
    #pragma unroll 1
    for (int kt = 0; kt < 4; ++kt) {
        const int tix = (kt + phase) & 3;     // this iteration's K-tile
        const short* cur = Wt[kt & 1];
        if (kt < 3) {                         // issue next tile into other buffer
            const int tnx = (kt + 1 + phase) & 3;
            const char* g = img + tnx * 32768 + wv * 4096 + lane * 16;
            char* l = (char*)&Wt[(kt + 1) & 1][wv * 2048];
            #pragma unroll
            for (int it = 0; it < 4; ++it)
                lds16(g + it * 1024, l + it * 1024);
        }

        float4 n0 = a0, n1 = a1, n2 = a2, n3 = a3;
        if (kt < 3) {                         // prefetch next tile's A-frags
            const int kn = ((kt + 1 + phase) & 3) * 64;
            n0 = *(const float4*)(xr + kn + q * 8);
            n1 = *(const float4*)(xr + kn + q * 8 + 4);
            n2 = *(const float4*)(xr + kn + 32 + q * 8);
            n3 = *(const float4*)(xr + kn + 32 + q * 8 + 4);
        }

        short8 af0 = pack8(a0, a1);           // k-local q*8..q*8+7
        short8 af1 = pack8(a2, a3);           // k-local 32+q*8..
        #pragma unroll
        for (int t = 0; t < 16; ++t) {
            const short* base = &cur[(t * 16 + c0) * 64];
            short8 bf0 = *(const short8*)&base[(q ^ vx) * 8];        // chunk q
            short8 bf1 = *(const short8*)&base[((q + 4) ^ vx) * 8];  // chunk q+4
            acc[t] = __builtin_amdgcn_mfma_f32_16x16x32_bf16(af0, bf0, acc[t], 0, 0, 0);
            acc[t] = __builtin_amdgcn_mfma_f32_16x16x32_bf16(af1, bf1, acc[t], 0, 0, 0);
        }
        __syncthreads();                      // tile consumed; next landed
        a0 = n0; a1 = n1; a2 = n2; a3 = n3;
    }

    // ---- epilogue: leaf sigmoid + tree (acc[t][r]: row q*4+r, leaf c0*16+t) ----
    float res[4];
    tree_reduce(acc, c0, pv, res);

    const int offs[4] = {240, 248, 252, 254};
    #pragma unroll
    for (int k = 0; k < 4; ++k) {             // levels 5-8: butterfly across c0
        float4 p = pv[offs[k] + (c0 >> (k + 1))];
        bool isLeft = ((c0 >> k) & 1) == 0;
        #pragma unroll
        for (int r = 0; r < 4; ++r) {
            float other = __shfl_xor(res[r], 1 << k, 64);
            float lf = isLeft ? res[r] : other;
            float rt = isLeft ? other  : res[r];
            res[r] = ggcd(lf * p.x, rt * p.y, p.z);
        }
    }

    if (c0 == 0) {
        const float wo = wout[0];
        const float bo = bout[0];
        #pragma unroll
        for (int r = 0; r < 4; ++r)
            out[rowbase + q * 4 + r] = fast_sigmoid(fmaf(res[r], wo, bo));
    }
}

extern "C" void kernel_launch(void* const* d_in, const int* in_sizes, int n_in,
                              void* d_out, int out_size, void* d_ws, size_t ws_size,
                              hipStream_t stream) {
    const float* x   = (const float*)d_in[0];
    const float* Wl  = (const float*)d_in[1];
    const float* wts = (const float*)d_in[2];
    const float* bia = (const float*)d_in[3];
    const float* wo  = (const float*)d_in[4];
    const float* bo  = (const float*)d_in[5];
    float* out = (float*)d_out;
    char* img = (char*)d_ws;                  // 128 KB W image + 4 KB params

    convert_w<<<dim3(64), dim3(256), 0, stream>>>(Wl, wts, bia, img);

    const int rows = out_size;                // 65536
    dim3 grid(rows / 128), block(512);        // 512 blocks x 8 waves, 2 blocks/CU
    btln_main<<<grid, block, 0, stream>>>(x, img, wo, bo, out);
}